// Round 4
// baseline (111.545 us; speedup 1.0000x reference)
//
#include <hip/hip_runtime.h>
#include <hip/hip_bf16.h>

// Fused flash-attention fwd: B=8,H=12,N=1024,D=64, fp32 in/out, bf16 MFMA.
// R13 = R9's exact compute (same macros, same register set/liveness) with a
// deeper DMA pipeline: K issued 3 phases ahead, V 2 phases ahead, into 3-slot
// LDS rings (48KB). Each phase: s_waitcnt vmcnt(4) (completes the 4-load group
// issued TWO phases ago -- the tiles this phase reads) + one s_barrier, then
// issue this phase's 4-load group. No vmcnt(0) drain in steady state (T4).
// Spill-hardening vs R12: ALL ring-slot indices are compile-time constants
// (6-phase superblock x2 + explicit tail; slot pattern period = 6), DMA issue
// at phase START (one-phase-extra latency cover), one barrier per phase, Q
// loaded+fenced before any DMA so manual vmcnt counts are exact.

typedef __attribute__((ext_vector_type(8))) __bf16 bf16x8;
typedef __attribute__((ext_vector_type(4))) float f32x4;
typedef __attribute__((ext_vector_type(16))) float f32x16;
typedef __attribute__((ext_vector_type(8))) unsigned short ushort8;
typedef __attribute__((ext_vector_type(2))) int int2v;

#define N_SEQ 1024
#define D_HEAD 64
#define QBLK 128
#define KBLK 64
#define NKT 16
#define NHEADS 96
#define TILE_ELEMS 4096   // 64x64 bf16 = 8KB per tensor per tile

static __device__ __forceinline__ unsigned short f2bf(float f) {
    __bf16 h = (__bf16)f;
    return __builtin_bit_cast(unsigned short, h);
}
static __device__ __forceinline__ unsigned pkbf(float a, float b) {
    union { unsigned short h[2]; unsigned u; } w;
    w.h[0] = f2bf(a); w.h[1] = f2bf(b);
    return w.u;      // v_cvt_pk_bf16_f32
}

// ------------- prep: K and V^T -> fragment-ordered bf16 tile images ---------
__global__ __launch_bounds__(256)
void prep_kv6(const float* __restrict__ K, const float* __restrict__ V,
              unsigned short* __restrict__ Kimg, unsigned short* __restrict__ Vimg)
{
    __shared__ float vt[64][65];

    const int j  = blockIdx.x;
    const int x  = j & 7;
    const int r  = j >> 3;
    const int h  = x + 8 * (r >> 4);
    const int kt = r & 15;

    const float* Kb = K + ((size_t)h * N_SEQ + kt * KBLK) * D_HEAD;
    const float* Vb = V + ((size_t)h * N_SEQ + kt * KBLK) * D_HEAD;
    unsigned short* Kt = Kimg + ((size_t)h * NKT + kt) * TILE_ELEMS;
    unsigned short* Vt = Vimg + ((size_t)h * NKT + kt) * TILE_ELEMS;

    const int tid = threadIdx.x;
    const int o   = tid >> 6;
    const int l   = tid & 63;
    const int m   = l & 31;
    const int hi  = l >> 5;

    {
        const int kvblk = o & 1, dblk0 = o >> 1;
        #pragma unroll
        for (int rep = 0; rep < 2; ++rep) {
            const int dblk = dblk0 + rep * 2;
            const float* src = Kb + (size_t)(kvblk * 32 + m) * D_HEAD + dblk * 16 + hi * 8;
            f32x4 a0 = *(const f32x4*)src, a1 = *(const f32x4*)(src + 4);
            union { unsigned short u[8]; ushort8 v; } w;
            #pragma unroll
            for (int e = 0; e < 4; ++e) { w.u[e] = f2bf(a0[e]); w.u[4+e] = f2bf(a1[e]); }
            *(ushort8*)&Kt[(dblk * 2 + kvblk) * 512 + l * 8] = w.v;
        }
    }
    {
        const int row = tid >> 2, c = tid & 3;
        const f32x4* src = (const f32x4*)(Vb + (size_t)row * D_HEAD + c * 16);
        f32x4 b0 = src[0], b1 = src[1], b2 = src[2], b3 = src[3];
        #pragma unroll
        for (int e = 0; e < 4; ++e) {
            vt[row][c*16 +      e] = b0[e];
            vt[row][c*16 +  4 + e] = b1[e];
            vt[row][c*16 +  8 + e] = b2[e];
            vt[row][c*16 + 12 + e] = b3[e];
        }
    }
    __syncthreads();
    {
        const int dblk2 = o & 1, jv0 = o >> 1;
        #pragma unroll
        for (int rep = 0; rep < 2; ++rep) {
            const int jv = jv0 + rep * 2;
            union { unsigned short u[8]; ushort8 v; } w;
            #pragma unroll
            for (int e = 0; e < 8; ++e)
                w.u[e] = f2bf(vt[jv * 16 + hi * 8 + e][dblk2 * 32 + m]);
            *(ushort8*)&Vt[(jv * 2 + dblk2) * 512 + l * 8] = w.v;
        }
    }
}

// ------------- main attention kernel ----------------------------------------
#define GLDS16(g, lp) \
    __builtin_amdgcn_global_load_lds((const __attribute__((address_space(1))) void*)(g), \
                                     (__attribute__((address_space(3))) void*)(lp), 16, 0, 0)

__global__ __launch_bounds__(256, 3)
void attn_fwd13(const float* __restrict__ Q,
                const unsigned short* __restrict__ Kimg,
                const unsigned short* __restrict__ Vimg,
                float* __restrict__ O)
{
    // K ring: slots 0..2, V ring: slots 3..5 (48 KB total)
    __shared__ unsigned short SHm[6 * TILE_ELEMS];

    const int tid  = threadIdx.x;
    const int wave = tid >> 6;
    const int lane = tid & 63;
    const int q32  = lane & 31;
    const int hi   = lane >> 5;

    const int j  = blockIdx.x;          // 768 blocks
    const int x  = j & 7;
    const int r  = j >> 3;
    const int bh = x + 8 * (r >> 3);    // XCD x owns 12 heads
    const int qt = r & 7;

    const float* Qb = Q + (size_t)bh * (N_SEQ * D_HEAD);
    float*       Ob = O + (size_t)bh * (N_SEQ * D_HEAD);
    const char*  KimgB = (const char*)(Kimg + (size_t)bh * NKT * TILE_ELEMS);
    const char*  VimgB = (const char*)(Vimg + (size_t)bh * NKT * TILE_ELEMS);

    const int stoff = tid * 16;

#define FENCE asm volatile("" ::: "memory")

#define ISSUE_K(kt_, s_) do {                                        \
        const char* g_ = KimgB + (size_t)(kt_) * 8192;               \
        char* l_ = (char*)&SHm[(s_) * TILE_ELEMS];                   \
        GLDS16(g_ + stoff,        l_ + stoff);                       \
        GLDS16(g_ + 4096 + stoff, l_ + 4096 + stoff);                \
    } while (0)
#define ISSUE_V(kt_, s_) do {                                        \
        const char* g_ = VimgB + (size_t)(kt_) * 8192;               \
        char* l_ = (char*)&SHm[(3 + (s_)) * TILE_ELEMS];             \
        GLDS16(g_ + stoff,        l_ + stoff);                       \
        GLDS16(g_ + 4096 + stoff, l_ + 4096 + stoff);                \
    } while (0)

    // ---- Q B-fragments FIRST (retire Q vmem before DMA count tracking)
    const float QSCALE = 0.125f * 1.44269504088896f;
    const int qrow = qt * QBLK + wave * 32 + q32;
    bf16x8 qb[4];
    #pragma unroll
    for (int dblk = 0; dblk < 4; ++dblk) {
        const float* qp = Qb + (size_t)qrow * D_HEAD + dblk * 16 + hi * 8;
        f32x4 a = *(const f32x4*)qp, b = *(const f32x4*)(qp + 4);
        union { unsigned short u[8]; bf16x8 v; } w;
        #pragma unroll
        for (int e = 0; e < 4; ++e) {
            w.u[e]     = f2bf(a[e] * QSCALE);
            w.u[4 + e] = f2bf(b[e] * QSCALE);
        }
        qb[dblk] = w.v;
    }
    bf16x8 ones;
    {
        union { unsigned short u[8]; bf16x8 v; } w;
        #pragma unroll
        for (int e = 0; e < 8; ++e) w.u[e] = 0x3F80;
        ones = w.v;
    }
    FENCE;   // Q loads ordered before all DMA issues

    // prologue DMA groups: {K0} | {K1,V0} | {K2,V1}  (10 loads)
    ISSUE_K(0, 0);
    FENCE;
    ISSUE_K(1, 1); ISSUE_V(0, 0);
    FENCE;
    ISSUE_K(2, 2); ISSUE_V(1, 1);

    f32x16 acc0 = {}, acc1 = {}, lacc = {};
    f32x16 SA0, SA1, SB0, SB1;

#define QK_TILE(S0_, S1_, ks_) do {                                              \
        const unsigned short* Klb_ = &SHm[(ks_) * TILE_ELEMS];                   \
        __builtin_amdgcn_s_setprio(1);                                           \
        _Pragma("unroll")                                                        \
        for (int dblk = 0; dblk < 4; ++dblk) {                                   \
            bf16x8 kf0 = *(const bf16x8*)&Klb_[(dblk * 2 + 0) * 512 + lane * 8]; \
            bf16x8 kf1 = *(const bf16x8*)&Klb_[(dblk * 2 + 1) * 512 + lane * 8]; \
            S0_ = __builtin_amdgcn_mfma_f32_32x32x16_bf16(kf0, qb[dblk], S0_, 0, 0, 0); \
            S1_ = __builtin_amdgcn_mfma_f32_32x32x16_bf16(kf1, qb[dblk], S1_, 0, 0, 0); \
        }                                                                        \
        __builtin_amdgcn_s_setprio(0);                                           \
    } while (0)

#if __has_builtin(__builtin_amdgcn_permlane32_swap)
#define MK_PA(dst_, P_, G0_) do {                                              \
            unsigned x0 = pkbf(P_[4*(G0_)+0], P_[4*(G0_)+1]);                  \
            unsigned x1 = pkbf(P_[4*(G0_)+2], P_[4*(G0_)+3]);                  \
            unsigned y0 = pkbf(P_[4*(G0_)+4], P_[4*(G0_)+5]);                  \
            unsigned y1 = pkbf(P_[4*(G0_)+6], P_[4*(G0_)+7]);                  \
            int2v r0 = __builtin_amdgcn_permlane32_swap((int)x0, (int)y0, false, false); \
            int2v r1 = __builtin_amdgcn_permlane32_swap((int)x1, (int)y1, false, false); \
            union { unsigned d[4]; bf16x8 v; } u_;                             \
            u_.d[0] = (unsigned)r0[0]; u_.d[1] = (unsigned)r1[0];              \
            u_.d[2] = (unsigned)r0[1]; u_.d[3] = (unsigned)r1[1];              \
            dst_ = u_.v;                                                       \
        } while (0)
#else
#define MK_PA(dst_, P_, G0_) do {                                              \
            unsigned x0 = pkbf(P_[4*(G0_)+0], P_[4*(G0_)+1]);                  \
            unsigned x1 = pkbf(P_[4*(G0_)+2], P_[4*(G0_)+3]);                  \
            unsigned y0 = pkbf(P_[4*(G0_)+4], P_[4*(G0_)+5]);                  \
            unsigned y1 = pkbf(P_[4*(G0_)+6], P_[4*(G0_)+7]);                  \
            unsigned sx0 = __shfl_xor(x0, 32), sx1 = __shfl_xor(x1, 32);       \
            unsigned sy0 = __shfl_xor(y0, 32), sy1 = __shfl_xor(y1, 32);       \
            union { unsigned d[4]; bf16x8 v; } u_;                             \
            u_.d[0] = hi ? sy0 : x0;  u_.d[1] = hi ? sy1 : x1;                 \
            u_.d[2] = hi ? y0  : sx0; u_.d[3] = hi ? y1  : sx1;               \
            dst_ = u_.v;                                                       \
        } while (0)
#endif

// exp/pack S -> pa0..3, then PV + lacc from V ring slot vs_ (R9 compute, verbatim)
#define SOFTMAX_PV(S0_, S1_, vs_) do {                                         \
        float p0[16], p1[16];                                                  \
        _Pragma("unroll")                                                      \
        for (int i = 0; i < 16; ++i) p0[i] = __builtin_amdgcn_exp2f(S0_[i]);   \
        _Pragma("unroll")                                                      \
        for (int i = 0; i < 16; ++i) p1[i] = __builtin_amdgcn_exp2f(S1_[i]);   \
        bf16x8 pa0, pa1, pa2, pa3;                                             \
        MK_PA(pa0, p0, 0);                                                     \
        MK_PA(pa1, p0, 2);                                                     \
        MK_PA(pa2, p1, 0);                                                     \
        MK_PA(pa3, p1, 2);                                                     \
        const unsigned short* Vtb_ = &SHm[(3 + (vs_)) * TILE_ELEMS];           \
        __builtin_amdgcn_s_setprio(1);                                         \
        bf16x8 vf;                                                             \
        vf = *(const bf16x8*)&Vtb_[(0*2+0)*512 + lane*8];                      \
        acc0 = __builtin_amdgcn_mfma_f32_32x32x16_bf16(vf, pa0, acc0, 0, 0, 0);\
        vf = *(const bf16x8*)&Vtb_[(0*2+1)*512 + lane*8];                      \
        acc1 = __builtin_amdgcn_mfma_f32_32x32x16_bf16(vf, pa0, acc1, 0, 0, 0);\
        vf = *(const bf16x8*)&Vtb_[(1*2+0)*512 + lane*8];                      \
        acc0 = __builtin_amdgcn_mfma_f32_32x32x16_bf16(vf, pa1, acc0, 0, 0, 0);\
        vf = *(const bf16x8*)&Vtb_[(1*2+1)*512 + lane*8];                      \
        acc1 = __builtin_amdgcn_mfma_f32_32x32x16_bf16(vf, pa1, acc1, 0, 0, 0);\
        vf = *(const bf16x8*)&Vtb_[(2*2+0)*512 + lane*8];                      \
        acc0 = __builtin_amdgcn_mfma_f32_32x32x16_bf16(vf, pa2, acc0, 0, 0, 0);\
        vf = *(const bf16x8*)&Vtb_[(2*2+1)*512 + lane*8];                      \
        acc1 = __builtin_amdgcn_mfma_f32_32x32x16_bf16(vf, pa2, acc1, 0, 0, 0);\
        vf = *(const bf16x8*)&Vtb_[(3*2+0)*512 + lane*8];                      \
        acc0 = __builtin_amdgcn_mfma_f32_32x32x16_bf16(vf, pa3, acc0, 0, 0, 0);\
        vf = *(const bf16x8*)&Vtb_[(3*2+1)*512 + lane*8];                      \
        acc1 = __builtin_amdgcn_mfma_f32_32x32x16_bf16(vf, pa3, acc1, 0, 0, 0);\
        lacc = __builtin_amdgcn_mfma_f32_32x32x16_bf16(ones, pa0, lacc, 0, 0, 0); \
        lacc = __builtin_amdgcn_mfma_f32_32x32x16_bf16(ones, pa1, lacc, 0, 0, 0); \
        lacc = __builtin_amdgcn_mfma_f32_32x32x16_bf16(ones, pa2, lacc, 0, 0, 0); \
        lacc = __builtin_amdgcn_mfma_f32_32x32x16_bf16(ones, pa3, lacc, 0, 0, 0); \
        __builtin_amdgcn_s_setprio(0);                                         \
    } while (0)

#define WAITN_BAR(N_) asm volatile("s_waitcnt vmcnt(" #N_ ")\n\ts_barrier" ::: "memory")

    // ---- prologue compute: wait {K0} (oldest group; Q retired first by its
    // own consumption + fence ordering), publish, QK(0).
    WAITN_BAR(8);
    SA0 = (f32x16){}; SA1 = (f32x16){};
    QK_TILE(SA0, SA1, 0);

    // Full phase p: wait group issued 2 phases ago (tiles this phase reads),
    // publish, issue {K(p+3)->slot (p)%3, V(p+2)->slot (p+2)%3}, then
    // QK(p+1) from slot (p+1)%3 and softmax+PV(p) from V slot p%3.
#define PH(p_, N0_, N1_, O0_, O1_, ks_, vs_, qs_, ps_) do {                    \
        WAITN_BAR(4);                                                          \
        ISSUE_K((p_) + 3, ks_);                                                \
        ISSUE_V((p_) + 2, vs_);                                                \
        N0_ = (f32x16){}; N1_ = (f32x16){};                                    \
        QK_TILE(N0_, N1_, qs_);                                                \
        SOFTMAX_PV(O0_, O1_, ps_);                                             \
    } while (0)

    // phases 0..11: two 6-phase superblocks (slot pattern period = 6)
    for (int blk = 0; blk < 2; ++blk) {
        const int tb = 6 * blk;
        PH(tb + 0, SB0, SB1, SA0, SA1, 0, 2, 1, 0);
        PH(tb + 1, SA0, SA1, SB0, SB1, 1, 0, 2, 1);
        PH(tb + 2, SB0, SB1, SA0, SA1, 2, 1, 0, 2);
        PH(tb + 3, SA0, SA1, SB0, SB1, 0, 2, 1, 0);
        PH(tb + 4, SB0, SB1, SA0, SA1, 1, 0, 2, 1);
        PH(tb + 5, SA0, SA1, SB0, SB1, 2, 1, 0, 2);
    }

    // phase 12 (last full phase: issues K15, V14)
    PH(12, SB0, SB1, SA0, SA1, 0, 2, 1, 0);

    // phase 13: issue V15 only
    WAITN_BAR(4);
    ISSUE_V(15, 0);
    SA0 = (f32x16){}; SA1 = (f32x16){};
    QK_TILE(SA0, SA1, 2);          // S(14)
    SOFTMAX_PV(SB0, SB1, 1);       // tile 13

    // phase 14: completes {K15,V14}
    WAITN_BAR(2);
    SB0 = (f32x16){}; SB1 = (f32x16){};
    QK_TILE(SB0, SB1, 0);          // S(15)
    SOFTMAX_PV(SA0, SA1, 2);       // tile 14

    // phase 15: completes {V15}
    WAITN_BAR(0);
    SOFTMAX_PV(SB0, SB1, 0);       // tile 15

    // ---- epilogue: transpose O^T -> O through reused LDS, per wave
    __syncthreads();
    float* tp = (float*)&SHm[0] + wave * 2048;
    const float inv = 1.0f / lacc[0];
    #pragma unroll
    for (int db = 0; db < 2; ++db) {
        #pragma unroll
        for (int reg = 0; reg < 16; ++reg) {
            const int d = db * 32 + (reg & 3) + 4 * hi + 8 * (reg >> 2);
            const int dwi = q32 * 64 + (((d >> 2) ^ (q32 & 15)) << 2) + (d & 3);
            tp[dwi] = (db ? acc1[reg] : acc0[reg]) * inv;
        }
    }
    asm volatile("s_waitcnt lgkmcnt(0)" ::: "memory");
    {
        const int q2 = lane >> 1, h2 = lane & 1;
        float* orow = Ob + (size_t)(qt * QBLK + wave * 32 + q2) * D_HEAD;
        #pragma unroll
        for (int c = 0; c < 8; ++c) {
            const int gd   = h2 * 8 + c;
            const int slot = gd ^ (q2 & 15);
            f32x4 v = *(const f32x4*)&tp[q2 * 64 + slot * 4];
            *(f32x4*)&orow[gd * 4] = v;
        }
    }
#undef PH
#undef ISSUE_K
#undef ISSUE_V
#undef QK_TILE
#undef SOFTMAX_PV
#undef MK_PA
#undef WAITN_BAR
#undef FENCE
}

// ------------- fallback (ws too small): R4 kernel ----------------------------
typedef __attribute__((ext_vector_type(8))) unsigned short ushort8_t;
static __device__ __forceinline__ int swz(int row, int b) {
    int slot = ((b >> 4) ^ (row & 7) ^ ((row >> 3) & 7)) & 7;
    return row * 128 + (slot << 4) + (b & 15);
}

__global__ __launch_bounds__(256, 4)
void attn_fwd4(const float* __restrict__ Q, const float* __restrict__ K,
               const float* __restrict__ V, float* __restrict__ O)
{
    __shared__ unsigned short KlBuf[2][64 * 64];
    __shared__ unsigned short VtBuf[2][64 * 64];
    __shared__ unsigned short Pl[4][16 * 64];

    const int tid  = threadIdx.x;
    const int wave = tid >> 6;
    const int lane = tid & 63;
    const int lg   = lane >> 4;
    const int li   = lane & 15;

    const int j  = blockIdx.x;
    const int x  = j & 7;
    const int r  = j >> 3;
    const int bh = x + 8 * (r >> 4);
    const int qt = r & 15;

    const size_t base = (size_t)bh * (N_SEQ * D_HEAD);
    const float* Qb = Q + base;
    const float* Kb = K + base;
    const float* Vb = V + base;
    float*       Ob = O + base;

    const float QSCALE = 0.125f * 1.44269504088896f;
    bf16x8 qfrag[2];
    {
        const float* qp = Qb + (size_t)(qt * 64 + wave * 16 + li) * D_HEAD;
        #pragma unroll
        for (int ks = 0; ks < 2; ++ks) {
            const f32x4* s4 = (const f32x4*)(qp + ks * 32 + lg * 8);
            f32x4 a = s4[0], b = s4[1];
            union { unsigned short u[8]; bf16x8 v; } w;
            #pragma unroll
            for (int e = 0; e < 4; ++e) {
                w.u[e]     = f2bf(a[e] * QSCALE);
                w.u[4 + e] = f2bf(b[e] * QSCALE);
            }
            qfrag[ks] = w.v;
        }
    }

    f32x4 acc[4];
    #pragma unroll
    for (int dc = 0; dc < 4; ++dc) { f32x4 z = {0.f,0.f,0.f,0.f}; acc[dc] = z; }
    float mrun = -1e30f, lrun = 0.f;

    const int kr = tid >> 2, kq = tid & 3;
    const int vp = tid >> 3, vc = tid & 7;

    f32x4 kreg[4], vreg[4];

#define ISSUE_LOADS(kt_) do {                                                          \
        const f32x4* ks4_ = (const f32x4*)(Kb + (size_t)((kt_) * KBLK + kr) * D_HEAD + kq * 16); \
        kreg[0] = ks4_[0]; kreg[1] = ks4_[1]; kreg[2] = ks4_[2]; kreg[3] = ks4_[3];    \
        const float* r0_ = Vb + (size_t)((kt_) * KBLK + 2 * vp) * D_HEAD + vc * 8;     \
        const f32x4* v0_ = (const f32x4*)r0_;                                          \
        const f32x4* v1_ = (const f32x4*)(r0_ + D_HEAD);                               \
        vreg[0] = v0_[0]; vreg[1] = v0_[1]; vreg[2] = v1_[0]; vreg[3] = v1_[1];        \
    } while (0)

#define WRITE_LDS(bufi_) do {                                                          \
        unsigned short* Klb_ = &KlBuf[bufi_][0];                                       \
        unsigned short* Vtb_ = &VtBuf[bufi_][0];                                       \
        union { unsigned short u[8]; ushort8_t v8; } w0_, w1_;                         \
        _Pragma("unroll")                                                              \
        for (int e = 0; e < 4; ++e) {                                                  \
            w0_.u[e]   = f2bf(kreg[0][e]); w0_.u[4+e] = f2bf(kreg[1][e]);              \
            w1_.u[e]   = f2bf(kreg[2][e]); w1_.u[4+e] = f2bf(kreg[3][e]);              \
        }                                                                              \
        *(ushort8_t*)&Klb_[swz(kr, kq * 32     ) >> 1] = w0_.v8;                       \
        *(ushort8_t*)&Klb_[swz(kr, kq * 32 + 16) >> 1] = w1_.v8;                       \
        _Pragma("unroll")                                                              \
        for (int e = 0; e < 8; ++e) {                                                  \
            float lo_ = (e < 4) ? vreg[0][e] : vreg[1][e - 4];                         \
            float hi_ = (e < 4) ? vreg[2][e] : vreg[3][e - 4];                         \
            unsigned pk_ = (unsigned)f2bf(lo_) | ((unsigned)f2bf(hi_) << 16);          \
            *(unsigned*)&Vtb_[swz(vc * 8 + e, vp * 4) >> 1] = pk_;                     \
        }                                                                              \
    } while (0)

    ISSUE_LOADS(0);
    WRITE_LDS(0);
    ISSUE_LOADS(1);
    asm volatile("s_waitcnt lgkmcnt(0)\n\ts_barrier" ::: "memory");

    for (int kt = 0; kt < NKT; ++kt) {
        const unsigned short* Klb = &KlBuf[kt & 1][0];
        const unsigned short* Vtb = &VtBuf[kt & 1][0];

        f32x4 s[4];
        #pragma unroll
        for (int nc = 0; nc < 4; ++nc) { f32x4 z = {0.f,0.f,0.f,0.f}; s[nc] = z; }
        #pragma unroll
        for (int nc = 0; nc < 4; ++nc) {
            #pragma unroll
            for (int ks = 0; ks < 2; ++ks) {
                bf16x8 kf = *(const bf16x8*)&Klb[swz(nc * 16 + li, ks * 64 + lg * 16) >> 1];
                s[nc] = __builtin_amdgcn_mfma_f32_16x16x32_bf16(kf, qfrag[ks], s[nc], 0, 0, 0);
            }
        }

        float t = s[0][0];
        #pragma unroll
        for (int nc = 0; nc < 4; ++nc)
            #pragma unroll
            for (int rr = 0; rr < 4; ++rr)
                t = fmaxf(t, s[nc][rr]);
        t = fmaxf(t, __shfl_xor(t, 16));
        t = fmaxf(t, __shfl_xor(t, 32));

        if (__any(t > mrun + 8.0f)) {
            const float mn  = fmaxf(mrun, t);
            const float fac = __builtin_amdgcn_exp2f(mrun - mn);
            mrun = mn;
            lrun *= fac;
            #pragma unroll
            for (int dc = 0; dc < 4; ++dc)
                #pragma unroll
                for (int rr = 0; rr < 4; ++rr)
                    acc[dc][rr] *= fac;
        }

        float p[4][4];
        float rs = 0.f;
        #pragma unroll
        for (int nc = 0; nc < 4; ++nc)
            #pragma unroll
            for (int rr = 0; rr < 4; ++rr) {
                p[nc][rr] = __builtin_amdgcn_exp2f(s[nc][rr] - mrun);
                rs += p[nc][rr];
            }
        rs += __shfl_xor(rs, 16);
        rs += __shfl_xor(rs, 32);
        lrun += rs;

        #pragma unroll
        for (int nc = 0; nc < 4; ++nc) {
            union { unsigned short u[4]; unsigned long long ll; } w;
            #pragma unroll
            for (int rr = 0; rr < 4; ++rr) w.u[rr] = f2bf(p[nc][rr]);
            *(unsigned long long*)&Pl[wave][swz(li, nc * 32 + lg * 8) >> 1] = w.ll;
        }

        #pragma unroll
        for (int ks = 0; ks < 2; ++ks) {
            bf16x8 pa = *(const bf16x8*)&Pl[wave][swz(li, ks * 64 + lg * 16) >> 1];
            #pragma unroll
            for (int dc = 0; dc < 4; ++dc) {
                bf16x8 vf = *(const bf16x8*)&Vtb[swz(dc * 16 + li, ks * 64 + lg * 16) >> 1];
                acc[dc] = __builtin_amdgcn_mfma_f32_16x16x32_bf16(vf, pa, acc[dc], 0, 0, 0);
            }
        }

        if (kt < NKT - 1) {
            WRITE_LDS((kt + 1) & 1);
            if (kt + 2 < NKT) ISSUE_LOADS(kt + 2);
            asm volatile("s_waitcnt lgkmcnt(0)\n\ts_barrier" ::: "memory");
        }
    }

    const float inv = 1.0f / lrun;
    const int orow = qt * 64 + wave * 16 + li;
    #pragma unroll
    for (int dc = 0; dc < 4; ++dc) {
        f32x4 o;
        #pragma unroll
        for (int rr = 0; rr < 4; ++rr) o[rr] = acc[dc][rr] * inv;
        *(f32x4*)&Ob[(size_t)orow * D_HEAD + dc * 16 + lg * 4] = o;
    }
#undef ISSUE_LOADS
#undef WRITE_LDS
}

extern "C" void kernel_launch(void* const* d_in, const int* in_sizes, int n_in,
                              void* d_out, int out_size, void* d_ws, size_t ws_size,
                              hipStream_t stream) {
    const float* Q = (const float*)d_in[0];
    const float* K = (const float*)d_in[1];
    const float* V = (const float*)d_in[2];
    float* O = (float*)d_out;

    const size_t img_elems = (size_t)NHEADS * NKT * TILE_ELEMS;
    const size_t need = img_elems * 2 * 2;   // bf16, K+V = 25.2 MB

    if (ws_size >= need) {
        unsigned short* Kimg = (unsigned short*)d_ws;
        unsigned short* Vimg = Kimg + img_elems;
        prep_kv6<<<dim3(NHEADS * NKT), dim3(256), 0, stream>>>(K, V, Kimg, Vimg);
        attn_fwd13<<<dim3(NHEADS * 8), dim3(256), 0, stream>>>(Q, Kimg, Vimg, O);
    } else {
        attn_fwd4<<<dim3(NHEADS * 16), dim3(256), 0, stream>>>(Q, K, V, O);
    }
}

// Round 5
// 56.089 us; speedup vs baseline: 1.9887x; 1.9887x over previous
//
#include <hip/hip_runtime.h>
#include <hip/hip_bf16.h>

// Fused flash-attention fwd: B=8,H=12,N=1024,D=64, fp32 in/out, bf16 MFMA.
// R14 = R9 verbatim (re-anchor). R10-R13 post-mortem: all three structural
// variants (VALU row-sum x2, 3-ring counted-vmcnt x2) spilled under
// __launch_bounds__(256,3) -- spill WRITE_SIZE rank-orders the regressions
// (13MB->59us, 24MB->63us, 300MB->111us vs 24.6MB clean->45.5us). R9's
// allocation is a razor-edge local optimum; occupancy is capped at 3
// blocks/CU by BOTH grid (768) and regfile (~148 unified/wave) so register
// diets cannot raise it. Counted-vmcnt needs register slack this structure
// does not have.

typedef __attribute__((ext_vector_type(8))) __bf16 bf16x8;
typedef __attribute__((ext_vector_type(4))) float f32x4;
typedef __attribute__((ext_vector_type(16))) float f32x16;
typedef __attribute__((ext_vector_type(8))) unsigned short ushort8;
typedef __attribute__((ext_vector_type(2))) int int2v;

#define N_SEQ 1024
#define D_HEAD 64
#define QBLK 128
#define KBLK 64
#define NKT 16
#define NHEADS 96
#define TILE_ELEMS 4096   // 64x64 bf16 = 8KB per tensor per tile

static __device__ __forceinline__ unsigned short f2bf(float f) {
    __bf16 h = (__bf16)f;
    return __builtin_bit_cast(unsigned short, h);
}
static __device__ __forceinline__ unsigned pkbf(float a, float b) {
    union { unsigned short h[2]; unsigned u; } w;
    w.h[0] = f2bf(a); w.h[1] = f2bf(b);
    return w.u;      // v_cvt_pk_bf16_f32
}

// ------------- prep: K and V^T -> fragment-ordered bf16 tile images ---------
__global__ __launch_bounds__(256)
void prep_kv6(const float* __restrict__ K, const float* __restrict__ V,
              unsigned short* __restrict__ Kimg, unsigned short* __restrict__ Vimg)
{
    __shared__ float vt[64][65];

    const int j  = blockIdx.x;
    const int x  = j & 7;
    const int r  = j >> 3;
    const int h  = x + 8 * (r >> 4);
    const int kt = r & 15;

    const float* Kb = K + ((size_t)h * N_SEQ + kt * KBLK) * D_HEAD;
    const float* Vb = V + ((size_t)h * N_SEQ + kt * KBLK) * D_HEAD;
    unsigned short* Kt = Kimg + ((size_t)h * NKT + kt) * TILE_ELEMS;
    unsigned short* Vt = Vimg + ((size_t)h * NKT + kt) * TILE_ELEMS;

    const int tid = threadIdx.x;
    const int o   = tid >> 6;
    const int l   = tid & 63;
    const int m   = l & 31;
    const int hi  = l >> 5;

    {
        const int kvblk = o & 1, dblk0 = o >> 1;
        #pragma unroll
        for (int rep = 0; rep < 2; ++rep) {
            const int dblk = dblk0 + rep * 2;
            const float* src = Kb + (size_t)(kvblk * 32 + m) * D_HEAD + dblk * 16 + hi * 8;
            f32x4 a0 = *(const f32x4*)src, a1 = *(const f32x4*)(src + 4);
            union { unsigned short u[8]; ushort8 v; } w;
            #pragma unroll
            for (int e = 0; e < 4; ++e) { w.u[e] = f2bf(a0[e]); w.u[4+e] = f2bf(a1[e]); }
            *(ushort8*)&Kt[(dblk * 2 + kvblk) * 512 + l * 8] = w.v;
        }
    }
    {
        const int row = tid >> 2, c = tid & 3;
        const f32x4* src = (const f32x4*)(Vb + (size_t)row * D_HEAD + c * 16);
        f32x4 b0 = src[0], b1 = src[1], b2 = src[2], b3 = src[3];
        #pragma unroll
        for (int e = 0; e < 4; ++e) {
            vt[row][c*16 +      e] = b0[e];
            vt[row][c*16 +  4 + e] = b1[e];
            vt[row][c*16 +  8 + e] = b2[e];
            vt[row][c*16 + 12 + e] = b3[e];
        }
    }
    __syncthreads();
    {
        const int dblk2 = o & 1, jv0 = o >> 1;
        #pragma unroll
        for (int rep = 0; rep < 2; ++rep) {
            const int jv = jv0 + rep * 2;
            union { unsigned short u[8]; ushort8 v; } w;
            #pragma unroll
            for (int e = 0; e < 8; ++e)
                w.u[e] = f2bf(vt[jv * 16 + hi * 8 + e][dblk2 * 32 + m]);
            *(ushort8*)&Vt[(jv * 2 + dblk2) * 512 + l * 8] = w.v;
        }
    }
}

// ------------- main attention kernel ----------------------------------------
#define GLDS16(g, lp) \
    __builtin_amdgcn_global_load_lds((const __attribute__((address_space(1))) void*)(g), \
                                     (__attribute__((address_space(3))) void*)(lp), 16, 0, 0)

__global__ __launch_bounds__(256, 3)
void attn_fwd9(const float* __restrict__ Q,
               const unsigned short* __restrict__ Kimg,
               const unsigned short* __restrict__ Vimg,
               float* __restrict__ O)
{
    __shared__ unsigned short SH[4][TILE_ELEMS];   // [0],[1]=K bufs; [2],[3]=V bufs (32 KB)

    const int tid  = threadIdx.x;
    const int wave = tid >> 6;
    const int lane = tid & 63;
    const int q32  = lane & 31;
    const int hi   = lane >> 5;

    const int j  = blockIdx.x;          // 768 blocks
    const int x  = j & 7;
    const int r  = j >> 3;
    const int bh = x + 8 * (r >> 3);    // XCD x owns 12 heads
    const int qt = r & 7;

    const float* Qb = Q + (size_t)bh * (N_SEQ * D_HEAD);
    float*       Ob = O + (size_t)bh * (N_SEQ * D_HEAD);
    const char*  KimgB = (const char*)(Kimg + (size_t)bh * NKT * TILE_ELEMS);
    const char*  VimgB = (const char*)(Vimg + (size_t)bh * NKT * TILE_ELEMS);

    const int stoff = tid * 16;

#define ISSUE_K(kt_, b_) do {                                        \
        const char* g_ = KimgB + (size_t)(kt_) * 8192;               \
        char* l_ = (char*)&SH[b_][0];                                \
        GLDS16(g_ + stoff,        l_ + stoff);                       \
        GLDS16(g_ + 4096 + stoff, l_ + 4096 + stoff);                \
    } while (0)
#define ISSUE_V(kt_, b_) do {                                        \
        const char* g_ = VimgB + (size_t)(kt_) * 8192;               \
        char* l_ = (char*)&SH[2 + (b_)][0];                          \
        GLDS16(g_ + stoff,        l_ + stoff);                       \
        GLDS16(g_ + 4096 + stoff, l_ + 4096 + stoff);                \
    } while (0)

    // prologue DMAs: K(0)->kb0, V(0)->vb0, K(1)->kb1
    ISSUE_K(0, 0);
    ISSUE_V(0, 0);
    ISSUE_K(1, 1);

    // ---- Q B-fragments
    const float QSCALE = 0.125f * 1.44269504088896f;
    const int qrow = qt * QBLK + wave * 32 + q32;
    bf16x8 qb[4];
    #pragma unroll
    for (int dblk = 0; dblk < 4; ++dblk) {
        const float* qp = Qb + (size_t)qrow * D_HEAD + dblk * 16 + hi * 8;
        f32x4 a = *(const f32x4*)qp, b = *(const f32x4*)(qp + 4);
        union { unsigned short u[8]; bf16x8 v; } w;
        #pragma unroll
        for (int e = 0; e < 4; ++e) {
            w.u[e]     = f2bf(a[e] * QSCALE);
            w.u[4 + e] = f2bf(b[e] * QSCALE);
        }
        qb[dblk] = w.v;
    }
    bf16x8 ones;
    {
        union { unsigned short u[8]; bf16x8 v; } w;
        #pragma unroll
        for (int e = 0; e < 8; ++e) w.u[e] = 0x3F80;
        ones = w.v;
    }

    f32x16 acc0 = {}, acc1 = {}, lacc = {};
    f32x16 SA0, SA1, SB0, SB1;

#define QK_TILE(S0_, S1_, kb_) do {                                              \
        const unsigned short* Klb_ = &SH[kb_][0];                                \
        __builtin_amdgcn_s_setprio(1);                                           \
        _Pragma("unroll")                                                        \
        for (int dblk = 0; dblk < 4; ++dblk) {                                   \
            bf16x8 kf0 = *(const bf16x8*)&Klb_[(dblk * 2 + 0) * 512 + lane * 8]; \
            bf16x8 kf1 = *(const bf16x8*)&Klb_[(dblk * 2 + 1) * 512 + lane * 8]; \
            S0_ = __builtin_amdgcn_mfma_f32_32x32x16_bf16(kf0, qb[dblk], S0_, 0, 0, 0); \
            S1_ = __builtin_amdgcn_mfma_f32_32x32x16_bf16(kf1, qb[dblk], S1_, 0, 0, 0); \
        }                                                                        \
        __builtin_amdgcn_s_setprio(0);                                           \
    } while (0)

#if __has_builtin(__builtin_amdgcn_permlane32_swap)
#define MK_PA(dst_, P_, G0_) do {                                              \
            unsigned x0 = pkbf(P_[4*(G0_)+0], P_[4*(G0_)+1]);                  \
            unsigned x1 = pkbf(P_[4*(G0_)+2], P_[4*(G0_)+3]);                  \
            unsigned y0 = pkbf(P_[4*(G0_)+4], P_[4*(G0_)+5]);                  \
            unsigned y1 = pkbf(P_[4*(G0_)+6], P_[4*(G0_)+7]);                  \
            int2v r0 = __builtin_amdgcn_permlane32_swap((int)x0, (int)y0, false, false); \
            int2v r1 = __builtin_amdgcn_permlane32_swap((int)x1, (int)y1, false, false); \
            union { unsigned d[4]; bf16x8 v; } u_;                             \
            u_.d[0] = (unsigned)r0[0]; u_.d[1] = (unsigned)r1[0];              \
            u_.d[2] = (unsigned)r0[1]; u_.d[3] = (unsigned)r1[1];              \
            dst_ = u_.v;                                                       \
        } while (0)
#else
#define MK_PA(dst_, P_, G0_) do {                                              \
            unsigned x0 = pkbf(P_[4*(G0_)+0], P_[4*(G0_)+1]);                  \
            unsigned x1 = pkbf(P_[4*(G0_)+2], P_[4*(G0_)+3]);                  \
            unsigned y0 = pkbf(P_[4*(G0_)+4], P_[4*(G0_)+5]);                  \
            unsigned y1 = pkbf(P_[4*(G0_)+6], P_[4*(G0_)+7]);                  \
            unsigned sx0 = __shfl_xor(x0, 32), sx1 = __shfl_xor(x1, 32);       \
            unsigned sy0 = __shfl_xor(y0, 32), sy1 = __shfl_xor(y1, 32);       \
            union { unsigned d[4]; bf16x8 v; } u_;                             \
            u_.d[0] = hi ? sy0 : x0;  u_.d[1] = hi ? sy1 : x1;                 \
            u_.d[2] = hi ? y0  : sx0; u_.d[3] = hi ? y1  : sx1;                \
            dst_ = u_.v;                                                       \
        } while (0)
#endif

// exp/pack S -> pa0..3, then PV + lacc from vbuf vb_ (SH index 2+vb_)
#define SOFTMAX_PV(S0_, S1_, vb_) do {                                         \
        float p0[16], p1[16];                                                  \
        _Pragma("unroll")                                                      \
        for (int i = 0; i < 16; ++i) p0[i] = __builtin_amdgcn_exp2f(S0_[i]);   \
        _Pragma("unroll")                                                      \
        for (int i = 0; i < 16; ++i) p1[i] = __builtin_amdgcn_exp2f(S1_[i]);   \
        bf16x8 pa0, pa1, pa2, pa3;                                             \
        MK_PA(pa0, p0, 0);                                                     \
        MK_PA(pa1, p0, 2);                                                     \
        MK_PA(pa2, p1, 0);                                                     \
        MK_PA(pa3, p1, 2);                                                     \
        const unsigned short* Vtb_ = &SH[2 + (vb_)][0];                        \
        __builtin_amdgcn_s_setprio(1);                                         \
        bf16x8 vf;                                                             \
        vf = *(const bf16x8*)&Vtb_[(0*2+0)*512 + lane*8];                      \
        acc0 = __builtin_amdgcn_mfma_f32_32x32x16_bf16(vf, pa0, acc0, 0, 0, 0);\
        vf = *(const bf16x8*)&Vtb_[(0*2+1)*512 + lane*8];                      \
        acc1 = __builtin_amdgcn_mfma_f32_32x32x16_bf16(vf, pa0, acc1, 0, 0, 0);\
        vf = *(const bf16x8*)&Vtb_[(1*2+0)*512 + lane*8];                      \
        acc0 = __builtin_amdgcn_mfma_f32_32x32x16_bf16(vf, pa1, acc0, 0, 0, 0);\
        vf = *(const bf16x8*)&Vtb_[(1*2+1)*512 + lane*8];                      \
        acc1 = __builtin_amdgcn_mfma_f32_32x32x16_bf16(vf, pa1, acc1, 0, 0, 0);\
        vf = *(const bf16x8*)&Vtb_[(2*2+0)*512 + lane*8];                      \
        acc0 = __builtin_amdgcn_mfma_f32_32x32x16_bf16(vf, pa2, acc0, 0, 0, 0);\
        vf = *(const bf16x8*)&Vtb_[(2*2+1)*512 + lane*8];                      \
        acc1 = __builtin_amdgcn_mfma_f32_32x32x16_bf16(vf, pa2, acc1, 0, 0, 0);\
        vf = *(const bf16x8*)&Vtb_[(3*2+0)*512 + lane*8];                      \
        acc0 = __builtin_amdgcn_mfma_f32_32x32x16_bf16(vf, pa3, acc0, 0, 0, 0);\
        vf = *(const bf16x8*)&Vtb_[(3*2+1)*512 + lane*8];                      \
        acc1 = __builtin_amdgcn_mfma_f32_32x32x16_bf16(vf, pa3, acc1, 0, 0, 0);\
        lacc = __builtin_amdgcn_mfma_f32_32x32x16_bf16(ones, pa0, lacc, 0, 0, 0); \
        lacc = __builtin_amdgcn_mfma_f32_32x32x16_bf16(ones, pa1, lacc, 0, 0, 0); \
        lacc = __builtin_amdgcn_mfma_f32_32x32x16_bf16(ones, pa2, lacc, 0, 0, 0); \
        lacc = __builtin_amdgcn_mfma_f32_32x32x16_bf16(ones, pa3, lacc, 0, 0, 0); \
        __builtin_amdgcn_s_setprio(0);                                         \
    } while (0)

#define WAITBAR asm volatile("s_waitcnt vmcnt(0)\n\ts_barrier" ::: "memory")

    WAITBAR;                           // K(0), V(0), K(1) ready
    SA0 = (f32x16){}; SA1 = (f32x16){};
    QK_TILE(SA0, SA1, 0);              // S(0) from kb0
    // RACE FIX: ensure ALL waves finished reading kb0 before any wave's
    // ISSUE_K(2, kb0) DMA (first loop iteration) can overwrite it.
    asm volatile("s_waitcnt lgkmcnt(0)\n\ts_barrier" ::: "memory");

    for (int it = 0; it < 8; ++it) {
        const int t = it * 2;
        // ---- phase A (tile t): overlap QK(t+1) with exp/pack(t)
        if (t + 2 < NKT) ISSUE_K(t + 2, 0);   // kb0: last read phase B prev iter (barrier'd)
        ISSUE_V(t + 1, 1);                    // vb1: last read phase B prev iter (barrier'd)
        SB0 = (f32x16){}; SB1 = (f32x16){};
        QK_TILE(SB0, SB1, 1);                 // S(t+1) from kb1
        SOFTMAX_PV(SA0, SA1, 0);              // exp/pack(t) + PV(t) from vb0
        WAITBAR;                              // K(t+2), V(t+1) landed; kb0/vb0 reads done

        // ---- phase B (tile t+1): overlap QK(t+2) with exp/pack(t+1)
        if (t + 3 < NKT) ISSUE_K(t + 3, 1);   // kb1: read in phase A (barrier'd)
        if (t + 2 < NKT) ISSUE_V(t + 2, 0);   // vb0: read in phase A (barrier'd)
        if (t + 2 < NKT) {
            SA0 = (f32x16){}; SA1 = (f32x16){};
            QK_TILE(SA0, SA1, 0);             // S(t+2) from kb0
        }
        SOFTMAX_PV(SB0, SB1, 1);              // exp/pack(t+1) + PV(t+1) from vb1
        if (it < 7) WAITBAR;                  // K(t+3), V(t+2) landed
    }

    // ---- epilogue: transpose O^T -> O through reused LDS, per wave
    __syncthreads();
    float* tp = (float*)&SH[0][0] + wave * 2048;
    const float inv = 1.0f / lacc[0];
    #pragma unroll
    for (int db = 0; db < 2; ++db) {
        #pragma unroll
        for (int reg = 0; reg < 16; ++reg) {
            const int d = db * 32 + (reg & 3) + 4 * hi + 8 * (reg >> 2);
            const int dwi = q32 * 64 + (((d >> 2) ^ (q32 & 15)) << 2) + (d & 3);
            tp[dwi] = (db ? acc1[reg] : acc0[reg]) * inv;
        }
    }
    asm volatile("s_waitcnt lgkmcnt(0)" ::: "memory");
    {
        const int q2 = lane >> 1, h2 = lane & 1;
        float* orow = Ob + (size_t)(qt * QBLK + wave * 32 + q2) * D_HEAD;
        #pragma unroll
        for (int c = 0; c < 8; ++c) {
            const int gd   = h2 * 8 + c;
            const int slot = gd ^ (q2 & 15);
            f32x4 v = *(const f32x4*)&tp[q2 * 64 + slot * 4];
            *(f32x4*)&orow[gd * 4] = v;
        }
    }
#undef ISSUE_K
#undef ISSUE_V
#undef QK_TILE
#undef SOFTMAX_PV
#undef MK_PA
#undef WAITBAR
}

// ------------- fallback (ws too small): R4 kernel ----------------------------
typedef __attribute__((ext_vector_type(8))) unsigned short ushort8_t;
static __device__ __forceinline__ int swz(int row, int b) {
    int slot = ((b >> 4) ^ (row & 7) ^ ((row >> 3) & 7)) & 7;
    return row * 128 + (slot << 4) + (b & 15);
}

__global__ __launch_bounds__(256, 4)
void attn_fwd4(const float* __restrict__ Q, const float* __restrict__ K,
               const float* __restrict__ V, float* __restrict__ O)
{
    __shared__ unsigned short KlBuf[2][64 * 64];
    __shared__ unsigned short VtBuf[2][64 * 64];
    __shared__ unsigned short Pl[4][16 * 64];

    const int tid  = threadIdx.x;
    const int wave = tid >> 6;
    const int lane = tid & 63;
    const int lg   = lane >> 4;
    const int li   = lane & 15;

    const int j  = blockIdx.x;
    const int x  = j & 7;
    const int r  = j >> 3;
    const int bh = x + 8 * (r >> 4);
    const int qt = r & 15;

    const size_t base = (size_t)bh * (N_SEQ * D_HEAD);
    const float* Qb = Q + base;
    const float* Kb = K + base;
    const float* Vb = V + base;
    float*       Ob = O + base;

    const float QSCALE = 0.125f * 1.44269504088896f;
    bf16x8 qfrag[2];
    {
        const float* qp = Qb + (size_t)(qt * 64 + wave * 16 + li) * D_HEAD;
        #pragma unroll
        for (int ks = 0; ks < 2; ++ks) {
            const f32x4* s4 = (const f32x4*)(qp + ks * 32 + lg * 8);
            f32x4 a = s4[0], b = s4[1];
            union { unsigned short u[8]; bf16x8 v; } w;
            #pragma unroll
            for (int e = 0; e < 4; ++e) {
                w.u[e]     = f2bf(a[e] * QSCALE);
                w.u[4 + e] = f2bf(b[e] * QSCALE);
            }
            qfrag[ks] = w.v;
        }
    }

    f32x4 acc[4];
    #pragma unroll
    for (int dc = 0; dc < 4; ++dc) { f32x4 z = {0.f,0.f,0.f,0.f}; acc[dc] = z; }
    float mrun = -1e30f, lrun = 0.f;

    const int kr = tid >> 2, kq = tid & 3;
    const int vp = tid >> 3, vc = tid & 7;

    f32x4 kreg[4], vreg[4];

#define ISSUE_LOADS(kt_) do {                                                          \
        const f32x4* ks4_ = (const f32x4*)(Kb + (size_t)((kt_) * KBLK + kr) * D_HEAD + kq * 16); \
        kreg[0] = ks4_[0]; kreg[1] = ks4_[1]; kreg[2] = ks4_[2]; kreg[3] = ks4_[3];    \
        const float* r0_ = Vb + (size_t)((kt_) * KBLK + 2 * vp) * D_HEAD + vc * 8;     \
        const f32x4* v0_ = (const f32x4*)r0_;                                          \
        const f32x4* v1_ = (const f32x4*)(r0_ + D_HEAD);                               \
        vreg[0] = v0_[0]; vreg[1] = v0_[1]; vreg[2] = v1_[0]; vreg[3] = v1_[1];        \
    } while (0)

#define WRITE_LDS(bufi_) do {                                                          \
        unsigned short* Klb_ = &KlBuf[bufi_][0];                                       \
        unsigned short* Vtb_ = &VtBuf[bufi_][0];                                       \
        union { unsigned short u[8]; ushort8_t v8; } w0_, w1_;                         \
        _Pragma("unroll")                                                              \
        for (int e = 0; e < 4; ++e) {                                                  \
            w0_.u[e]   = f2bf(kreg[0][e]); w0_.u[4+e] = f2bf(kreg[1][e]);              \
            w1_.u[e]   = f2bf(kreg[2][e]); w1_.u[4+e] = f2bf(kreg[3][e]);              \
        }                                                                              \
        *(ushort8_t*)&Klb_[swz(kr, kq * 32     ) >> 1] = w0_.v8;                       \
        *(ushort8_t*)&Klb_[swz(kr, kq * 32 + 16) >> 1] = w1_.v8;                       \
        _Pragma("unroll")                                                              \
        for (int e = 0; e < 8; ++e) {                                                  \
            float lo_ = (e < 4) ? vreg[0][e] : vreg[1][e - 4];                         \
            float hi_ = (e < 4) ? vreg[2][e] : vreg[3][e - 4];                         \
            unsigned pk_ = (unsigned)f2bf(lo_) | ((unsigned)f2bf(hi_) << 16);          \
            *(unsigned*)&Vtb_[swz(vc * 8 + e, vp * 4) >> 1] = pk_;                     \
        }                                                                              \
    } while (0)

    ISSUE_LOADS(0);
    WRITE_LDS(0);
    ISSUE_LOADS(1);
    asm volatile("s_waitcnt lgkmcnt(0)\n\ts_barrier" ::: "memory");

    for (int kt = 0; kt < NKT; ++kt) {
        const unsigned short* Klb = &KlBuf[kt & 1][0];
        const unsigned short* Vtb = &VtBuf[kt & 1][0];

        f32x4 s[4];
        #pragma unroll
        for (int nc = 0; nc < 4; ++nc) { f32x4 z = {0.f,0.f,0.f,0.f}; s[nc] = z; }
        #pragma unroll
        for (int nc = 0; nc < 4; ++nc) {
            #pragma unroll
            for (int ks = 0; ks < 2; ++ks) {
                bf16x8 kf = *(const bf16x8*)&Klb[swz(nc * 16 + li, ks * 64 + lg * 16) >> 1];
                s[nc] = __builtin_amdgcn_mfma_f32_16x16x32_bf16(kf, qfrag[ks], s[nc], 0, 0, 0);
            }
        }

        float t = s[0][0];
        #pragma unroll
        for (int nc = 0; nc < 4; ++nc)
            #pragma unroll
            for (int rr = 0; rr < 4; ++rr)
                t = fmaxf(t, s[nc][rr]);
        t = fmaxf(t, __shfl_xor(t, 16));
        t = fmaxf(t, __shfl_xor(t, 32));

        if (__any(t > mrun + 8.0f)) {
            const float mn  = fmaxf(mrun, t);
            const float fac = __builtin_amdgcn_exp2f(mrun - mn);
            mrun = mn;
            lrun *= fac;
            #pragma unroll
            for (int dc = 0; dc < 4; ++dc)
                #pragma unroll
                for (int rr = 0; rr < 4; ++rr)
                    acc[dc][rr] *= fac;
        }

        float p[4][4];
        float rs = 0.f;
        #pragma unroll
        for (int nc = 0; nc < 4; ++nc)
            #pragma unroll
            for (int rr = 0; rr < 4; ++rr) {
                p[nc][rr] = __builtin_amdgcn_exp2f(s[nc][rr] - mrun);
                rs += p[nc][rr];
            }
        rs += __shfl_xor(rs, 16);
        rs += __shfl_xor(rs, 32);
        lrun += rs;

        #pragma unroll
        for (int nc = 0; nc < 4; ++nc) {
            union { unsigned short u[4]; unsigned long long ll; } w;
            #pragma unroll
            for (int rr = 0; rr < 4; ++rr) w.u[rr] = f2bf(p[nc][rr]);
            *(unsigned long long*)&Pl[wave][swz(li, nc * 32 + lg * 8) >> 1] = w.ll;
        }

        #pragma unroll
        for (int ks = 0; ks < 2; ++ks) {
            bf16x8 pa = *(const bf16x8*)&Pl[wave][swz(li, ks * 64 + lg * 16) >> 1];
            #pragma unroll
            for (int dc = 0; dc < 4; ++dc) {
                bf16x8 vf = *(const bf16x8*)&Vtb[swz(dc * 16 + li, ks * 64 + lg * 16) >> 1];
                acc[dc] = __builtin_amdgcn_mfma_f32_16x16x32_bf16(vf, pa, acc[dc], 0, 0, 0);
            }
        }

        if (kt < NKT - 1) {
            WRITE_LDS((kt + 1) & 1);
            if (kt + 2 < NKT) ISSUE_LOADS(kt + 2);
            asm volatile("s_waitcnt lgkmcnt(0)\n\ts_barrier" ::: "memory");
        }
    }

    const float inv = 1.0f / lrun;
    const int orow = qt * 64 + wave * 16 + li;
    #pragma unroll
    for (int dc = 0; dc < 4; ++dc) {
        f32x4 o;
        #pragma unroll
        for (int rr = 0; rr < 4; ++rr) o[rr] = acc[dc][rr] * inv;
        *(f32x4*)&Ob[(size_t)orow * D_HEAD + dc * 16 + lg * 4] = o;
    }
#undef ISSUE_LOADS
#undef WRITE_LDS
}

extern "C" void kernel_launch(void* const* d_in, const int* in_sizes, int n_in,
                              void* d_out, int out_size, void* d_ws, size_t ws_size,
                              hipStream_t stream) {
    const float* Q = (const float*)d_in[0];
    const float* K = (const float*)d_in[1];
    const float* V = (const float*)d_in[2];
    float* O = (float*)d_out;

    const size_t img_elems = (size_t)NHEADS * NKT * TILE_ELEMS;
    const size_t need = img_elems * 2 * 2;   // bf16, K+V = 25.2 MB

    if (ws_size >= need) {
        unsigned short* Kimg = (unsigned short*)d_ws;
        unsigned short* Vimg = Kimg + img_elems;
        prep_kv6<<<dim3(NHEADS * NKT), dim3(256), 0, stream>>>(K, V, Kimg, Vimg);
        attn_fwd9<<<dim3(NHEADS * 8), dim3(256), 0, stream>>>(Q, Kimg, Vimg, O);
    } else {
        attn_fwd4<<<dim3(NHEADS * 16), dim3(256), 0, stream>>>(Q, K, V, O);
    }
}

// Round 6
// 55.485 us; speedup vs baseline: 2.0103x; 1.0109x over previous
//
#include <hip/hip_runtime.h>
#include <hip/hip_bf16.h>

// Fused flash-attention fwd: B=8,H=12,N=1024,D=64, fp32 in/out, bf16 MFMA.
// R15 = R9 minus ALL s_setprio toggles. Rationale: (1) the setprio asm
// volatiles fence the scheduler -- exp/pack VALU (independent, ready at
// phase start) cannot be interleaved into the MFMA shadow of the 4-deep
// S0/S1 dependency chains; (2) T5's prerequisite (wave role-diversity) is
// absent here: each SIMD hosts 3 waves from identically-coded blocks, so
// priority-boosting MFMA regions starves neighbor waves' VALU issue (m190
// precedent). Zero liveness/structural change vs R9 -> no spill risk.

typedef __attribute__((ext_vector_type(8))) __bf16 bf16x8;
typedef __attribute__((ext_vector_type(4))) float f32x4;
typedef __attribute__((ext_vector_type(16))) float f32x16;
typedef __attribute__((ext_vector_type(8))) unsigned short ushort8;
typedef __attribute__((ext_vector_type(2))) int int2v;

#define N_SEQ 1024
#define D_HEAD 64
#define QBLK 128
#define KBLK 64
#define NKT 16
#define NHEADS 96
#define TILE_ELEMS 4096   // 64x64 bf16 = 8KB per tensor per tile

static __device__ __forceinline__ unsigned short f2bf(float f) {
    __bf16 h = (__bf16)f;
    return __builtin_bit_cast(unsigned short, h);
}
static __device__ __forceinline__ unsigned pkbf(float a, float b) {
    union { unsigned short h[2]; unsigned u; } w;
    w.h[0] = f2bf(a); w.h[1] = f2bf(b);
    return w.u;      // v_cvt_pk_bf16_f32
}

// ------------- prep: K and V^T -> fragment-ordered bf16 tile images ---------
__global__ __launch_bounds__(256)
void prep_kv6(const float* __restrict__ K, const float* __restrict__ V,
              unsigned short* __restrict__ Kimg, unsigned short* __restrict__ Vimg)
{
    __shared__ float vt[64][65];

    const int j  = blockIdx.x;
    const int x  = j & 7;
    const int r  = j >> 3;
    const int h  = x + 8 * (r >> 4);
    const int kt = r & 15;

    const float* Kb = K + ((size_t)h * N_SEQ + kt * KBLK) * D_HEAD;
    const float* Vb = V + ((size_t)h * N_SEQ + kt * KBLK) * D_HEAD;
    unsigned short* Kt = Kimg + ((size_t)h * NKT + kt) * TILE_ELEMS;
    unsigned short* Vt = Vimg + ((size_t)h * NKT + kt) * TILE_ELEMS;

    const int tid = threadIdx.x;
    const int o   = tid >> 6;
    const int l   = tid & 63;
    const int m   = l & 31;
    const int hi  = l >> 5;

    {
        const int kvblk = o & 1, dblk0 = o >> 1;
        #pragma unroll
        for (int rep = 0; rep < 2; ++rep) {
            const int dblk = dblk0 + rep * 2;
            const float* src = Kb + (size_t)(kvblk * 32 + m) * D_HEAD + dblk * 16 + hi * 8;
            f32x4 a0 = *(const f32x4*)src, a1 = *(const f32x4*)(src + 4);
            union { unsigned short u[8]; ushort8 v; } w;
            #pragma unroll
            for (int e = 0; e < 4; ++e) { w.u[e] = f2bf(a0[e]); w.u[4+e] = f2bf(a1[e]); }
            *(ushort8*)&Kt[(dblk * 2 + kvblk) * 512 + l * 8] = w.v;
        }
    }
    {
        const int row = tid >> 2, c = tid & 3;
        const f32x4* src = (const f32x4*)(Vb + (size_t)row * D_HEAD + c * 16);
        f32x4 b0 = src[0], b1 = src[1], b2 = src[2], b3 = src[3];
        #pragma unroll
        for (int e = 0; e < 4; ++e) {
            vt[row][c*16 +      e] = b0[e];
            vt[row][c*16 +  4 + e] = b1[e];
            vt[row][c*16 +  8 + e] = b2[e];
            vt[row][c*16 + 12 + e] = b3[e];
        }
    }
    __syncthreads();
    {
        const int dblk2 = o & 1, jv0 = o >> 1;
        #pragma unroll
        for (int rep = 0; rep < 2; ++rep) {
            const int jv = jv0 + rep * 2;
            union { unsigned short u[8]; ushort8 v; } w;
            #pragma unroll
            for (int e = 0; e < 8; ++e)
                w.u[e] = f2bf(vt[jv * 16 + hi * 8 + e][dblk2 * 32 + m]);
            *(ushort8*)&Vt[(jv * 2 + dblk2) * 512 + l * 8] = w.v;
        }
    }
}

// ------------- main attention kernel ----------------------------------------
#define GLDS16(g, lp) \
    __builtin_amdgcn_global_load_lds((const __attribute__((address_space(1))) void*)(g), \
                                     (__attribute__((address_space(3))) void*)(lp), 16, 0, 0)

__global__ __launch_bounds__(256, 3)
void attn_fwd15(const float* __restrict__ Q,
                const unsigned short* __restrict__ Kimg,
                const unsigned short* __restrict__ Vimg,
                float* __restrict__ O)
{
    __shared__ unsigned short SH[4][TILE_ELEMS];   // [0],[1]=K bufs; [2],[3]=V bufs (32 KB)

    const int tid  = threadIdx.x;
    const int wave = tid >> 6;
    const int lane = tid & 63;
    const int q32  = lane & 31;
    const int hi   = lane >> 5;

    const int j  = blockIdx.x;          // 768 blocks
    const int x  = j & 7;
    const int r  = j >> 3;
    const int bh = x + 8 * (r >> 3);    // XCD x owns 12 heads
    const int qt = r & 7;

    const float* Qb = Q + (size_t)bh * (N_SEQ * D_HEAD);
    float*       Ob = O + (size_t)bh * (N_SEQ * D_HEAD);
    const char*  KimgB = (const char*)(Kimg + (size_t)bh * NKT * TILE_ELEMS);
    const char*  VimgB = (const char*)(Vimg + (size_t)bh * NKT * TILE_ELEMS);

    const int stoff = tid * 16;

#define ISSUE_K(kt_, b_) do {                                        \
        const char* g_ = KimgB + (size_t)(kt_) * 8192;               \
        char* l_ = (char*)&SH[b_][0];                                \
        GLDS16(g_ + stoff,        l_ + stoff);                       \
        GLDS16(g_ + 4096 + stoff, l_ + 4096 + stoff);                \
    } while (0)
#define ISSUE_V(kt_, b_) do {                                        \
        const char* g_ = VimgB + (size_t)(kt_) * 8192;               \
        char* l_ = (char*)&SH[2 + (b_)][0];                          \
        GLDS16(g_ + stoff,        l_ + stoff);                       \
        GLDS16(g_ + 4096 + stoff, l_ + 4096 + stoff);                \
    } while (0)

    // prologue DMAs: K(0)->kb0, V(0)->vb0, K(1)->kb1
    ISSUE_K(0, 0);
    ISSUE_V(0, 0);
    ISSUE_K(1, 1);

    // ---- Q B-fragments
    const float QSCALE = 0.125f * 1.44269504088896f;
    const int qrow = qt * QBLK + wave * 32 + q32;
    bf16x8 qb[4];
    #pragma unroll
    for (int dblk = 0; dblk < 4; ++dblk) {
        const float* qp = Qb + (size_t)qrow * D_HEAD + dblk * 16 + hi * 8;
        f32x4 a = *(const f32x4*)qp, b = *(const f32x4*)(qp + 4);
        union { unsigned short u[8]; bf16x8 v; } w;
        #pragma unroll
        for (int e = 0; e < 4; ++e) {
            w.u[e]     = f2bf(a[e] * QSCALE);
            w.u[4 + e] = f2bf(b[e] * QSCALE);
        }
        qb[dblk] = w.v;
    }
    bf16x8 ones;
    {
        union { unsigned short u[8]; bf16x8 v; } w;
        #pragma unroll
        for (int e = 0; e < 8; ++e) w.u[e] = 0x3F80;
        ones = w.v;
    }

    f32x16 acc0 = {}, acc1 = {}, lacc = {};
    f32x16 SA0, SA1, SB0, SB1;

#define QK_TILE(S0_, S1_, kb_) do {                                              \
        const unsigned short* Klb_ = &SH[kb_][0];                                \
        _Pragma("unroll")                                                        \
        for (int dblk = 0; dblk < 4; ++dblk) {                                   \
            bf16x8 kf0 = *(const bf16x8*)&Klb_[(dblk * 2 + 0) * 512 + lane * 8]; \
            bf16x8 kf1 = *(const bf16x8*)&Klb_[(dblk * 2 + 1) * 512 + lane * 8]; \
            S0_ = __builtin_amdgcn_mfma_f32_32x32x16_bf16(kf0, qb[dblk], S0_, 0, 0, 0); \
            S1_ = __builtin_amdgcn_mfma_f32_32x32x16_bf16(kf1, qb[dblk], S1_, 0, 0, 0); \
        }                                                                        \
    } while (0)

#if __has_builtin(__builtin_amdgcn_permlane32_swap)
#define MK_PA(dst_, P_, G0_) do {                                              \
            unsigned x0 = pkbf(P_[4*(G0_)+0], P_[4*(G0_)+1]);                  \
            unsigned x1 = pkbf(P_[4*(G0_)+2], P_[4*(G0_)+3]);                  \
            unsigned y0 = pkbf(P_[4*(G0_)+4], P_[4*(G0_)+5]);                  \
            unsigned y1 = pkbf(P_[4*(G0_)+6], P_[4*(G0_)+7]);                  \
            int2v r0 = __builtin_amdgcn_permlane32_swap((int)x0, (int)y0, false, false); \
            int2v r1 = __builtin_amdgcn_permlane32_swap((int)x1, (int)y1, false, false); \
            union { unsigned d[4]; bf16x8 v; } u_;                             \
            u_.d[0] = (unsigned)r0[0]; u_.d[1] = (unsigned)r1[0];              \
            u_.d[2] = (unsigned)r0[1]; u_.d[3] = (unsigned)r1[1];              \
            dst_ = u_.v;                                                       \
        } while (0)
#else
#define MK_PA(dst_, P_, G0_) do {                                              \
            unsigned x0 = pkbf(P_[4*(G0_)+0], P_[4*(G0_)+1]);                  \
            unsigned x1 = pkbf(P_[4*(G0_)+2], P_[4*(G0_)+3]);                  \
            unsigned y0 = pkbf(P_[4*(G0_)+4], P_[4*(G0_)+5]);                  \
            unsigned y1 = pkbf(P_[4*(G0_)+6], P_[4*(G0_)+7]);                  \
            unsigned sx0 = __shfl_xor(x0, 32), sx1 = __shfl_xor(x1, 32);       \
            unsigned sy0 = __shfl_xor(y0, 32), sy1 = __shfl_xor(y1, 32);       \
            union { unsigned d[4]; bf16x8 v; } u_;                             \
            u_.d[0] = hi ? sy0 : x0;  u_.d[1] = hi ? sy1 : x1;                 \
            u_.d[2] = hi ? y0  : sx0; u_.d[3] = hi ? y1  : sx1;                \
            dst_ = u_.v;                                                       \
        } while (0)
#endif

// exp/pack S -> pa0..3, then PV + lacc from vbuf vb_ (SH index 2+vb_)
#define SOFTMAX_PV(S0_, S1_, vb_) do {                                         \
        float p0[16], p1[16];                                                  \
        _Pragma("unroll")                                                      \
        for (int i = 0; i < 16; ++i) p0[i] = __builtin_amdgcn_exp2f(S0_[i]);   \
        _Pragma("unroll")                                                      \
        for (int i = 0; i < 16; ++i) p1[i] = __builtin_amdgcn_exp2f(S1_[i]);   \
        bf16x8 pa0, pa1, pa2, pa3;                                             \
        MK_PA(pa0, p0, 0);                                                     \
        MK_PA(pa1, p0, 2);                                                     \
        MK_PA(pa2, p1, 0);                                                     \
        MK_PA(pa3, p1, 2);                                                     \
        const unsigned short* Vtb_ = &SH[2 + (vb_)][0];                        \
        bf16x8 vf;                                                             \
        vf = *(const bf16x8*)&Vtb_[(0*2+0)*512 + lane*8];                      \
        acc0 = __builtin_amdgcn_mfma_f32_32x32x16_bf16(vf, pa0, acc0, 0, 0, 0);\
        vf = *(const bf16x8*)&Vtb_[(0*2+1)*512 + lane*8];                      \
        acc1 = __builtin_amdgcn_mfma_f32_32x32x16_bf16(vf, pa0, acc1, 0, 0, 0);\
        vf = *(const bf16x8*)&Vtb_[(1*2+0)*512 + lane*8];                      \
        acc0 = __builtin_amdgcn_mfma_f32_32x32x16_bf16(vf, pa1, acc0, 0, 0, 0);\
        vf = *(const bf16x8*)&Vtb_[(1*2+1)*512 + lane*8];                      \
        acc1 = __builtin_amdgcn_mfma_f32_32x32x16_bf16(vf, pa1, acc1, 0, 0, 0);\
        vf = *(const bf16x8*)&Vtb_[(2*2+0)*512 + lane*8];                      \
        acc0 = __builtin_amdgcn_mfma_f32_32x32x16_bf16(vf, pa2, acc0, 0, 0, 0);\
        vf = *(const bf16x8*)&Vtb_[(2*2+1)*512 + lane*8];                      \
        acc1 = __builtin_amdgcn_mfma_f32_32x32x16_bf16(vf, pa2, acc1, 0, 0, 0);\
        vf = *(const bf16x8*)&Vtb_[(3*2+0)*512 + lane*8];                      \
        acc0 = __builtin_amdgcn_mfma_f32_32x32x16_bf16(vf, pa3, acc0, 0, 0, 0);\
        vf = *(const bf16x8*)&Vtb_[(3*2+1)*512 + lane*8];                      \
        acc1 = __builtin_amdgcn_mfma_f32_32x32x16_bf16(vf, pa3, acc1, 0, 0, 0);\
        lacc = __builtin_amdgcn_mfma_f32_32x32x16_bf16(ones, pa0, lacc, 0, 0, 0); \
        lacc = __builtin_amdgcn_mfma_f32_32x32x16_bf16(ones, pa1, lacc, 0, 0, 0); \
        lacc = __builtin_amdgcn_mfma_f32_32x32x16_bf16(ones, pa2, lacc, 0, 0, 0); \
        lacc = __builtin_amdgcn_mfma_f32_32x32x16_bf16(ones, pa3, lacc, 0, 0, 0); \
    } while (0)

#define WAITBAR asm volatile("s_waitcnt vmcnt(0)\n\ts_barrier" ::: "memory")

    WAITBAR;                           // K(0), V(0), K(1) ready
    SA0 = (f32x16){}; SA1 = (f32x16){};
    QK_TILE(SA0, SA1, 0);              // S(0) from kb0
    // RACE FIX: ensure ALL waves finished reading kb0 before any wave's
    // ISSUE_K(2, kb0) DMA (first loop iteration) can overwrite it.
    asm volatile("s_waitcnt lgkmcnt(0)\n\ts_barrier" ::: "memory");

    for (int it = 0; it < 8; ++it) {
        const int t = it * 2;
        // ---- phase A (tile t): overlap QK(t+1) with exp/pack(t)
        if (t + 2 < NKT) ISSUE_K(t + 2, 0);   // kb0: last read phase B prev iter (barrier'd)
        ISSUE_V(t + 1, 1);                    // vb1: last read phase B prev iter (barrier'd)
        SB0 = (f32x16){}; SB1 = (f32x16){};
        QK_TILE(SB0, SB1, 1);                 // S(t+1) from kb1
        SOFTMAX_PV(SA0, SA1, 0);              // exp/pack(t) + PV(t) from vb0
        WAITBAR;                              // K(t+2), V(t+1) landed; kb0/vb0 reads done

        // ---- phase B (tile t+1): overlap QK(t+2) with exp/pack(t+1)
        if (t + 3 < NKT) ISSUE_K(t + 3, 1);   // kb1: read in phase A (barrier'd)
        if (t + 2 < NKT) ISSUE_V(t + 2, 0);   // vb0: read in phase A (barrier'd)
        if (t + 2 < NKT) {
            SA0 = (f32x16){}; SA1 = (f32x16){};
            QK_TILE(SA0, SA1, 0);             // S(t+2) from kb0
        }
        SOFTMAX_PV(SB0, SB1, 1);              // exp/pack(t+1) + PV(t+1) from vb1
        if (it < 7) WAITBAR;                  // K(t+3), V(t+2) landed
    }

    // ---- epilogue: transpose O^T -> O through reused LDS, per wave
    __syncthreads();
    float* tp = (float*)&SH[0][0] + wave * 2048;
    const float inv = 1.0f / lacc[0];
    #pragma unroll
    for (int db = 0; db < 2; ++db) {
        #pragma unroll
        for (int reg = 0; reg < 16; ++reg) {
            const int d = db * 32 + (reg & 3) + 4 * hi + 8 * (reg >> 2);
            const int dwi = q32 * 64 + (((d >> 2) ^ (q32 & 15)) << 2) + (d & 3);
            tp[dwi] = (db ? acc1[reg] : acc0[reg]) * inv;
        }
    }
    asm volatile("s_waitcnt lgkmcnt(0)" ::: "memory");
    {
        const int q2 = lane >> 1, h2 = lane & 1;
        float* orow = Ob + (size_t)(qt * QBLK + wave * 32 + q2) * D_HEAD;
        #pragma unroll
        for (int c = 0; c < 8; ++c) {
            const int gd   = h2 * 8 + c;
            const int slot = gd ^ (q2 & 15);
            f32x4 v = *(const f32x4*)&tp[q2 * 64 + slot * 4];
            *(f32x4*)&orow[gd * 4] = v;
        }
    }
#undef ISSUE_K
#undef ISSUE_V
#undef QK_TILE
#undef SOFTMAX_PV
#undef MK_PA
#undef WAITBAR
}

// ------------- fallback (ws too small): R4 kernel ----------------------------
typedef __attribute__((ext_vector_type(8))) unsigned short ushort8_t;
static __device__ __forceinline__ int swz(int row, int b) {
    int slot = ((b >> 4) ^ (row & 7) ^ ((row >> 3) & 7)) & 7;
    return row * 128 + (slot << 4) + (b & 15);
}

__global__ __launch_bounds__(256, 4)
void attn_fwd4(const float* __restrict__ Q, const float* __restrict__ K,
               const float* __restrict__ V, float* __restrict__ O)
{
    __shared__ unsigned short KlBuf[2][64 * 64];
    __shared__ unsigned short VtBuf[2][64 * 64];
    __shared__ unsigned short Pl[4][16 * 64];

    const int tid  = threadIdx.x;
    const int wave = tid >> 6;
    const int lane = tid & 63;
    const int lg   = lane >> 4;
    const int li   = lane & 15;

    const int j  = blockIdx.x;
    const int x  = j & 7;
    const int r  = j >> 3;
    const int bh = x + 8 * (r >> 4);
    const int qt = r & 15;

    const size_t base = (size_t)bh * (N_SEQ * D_HEAD);
    const float* Qb = Q + base;
    const float* Kb = K + base;
    const float* Vb = V + base;
    float*       Ob = O + base;

    const float QSCALE = 0.125f * 1.44269504088896f;
    bf16x8 qfrag[2];
    {
        const float* qp = Qb + (size_t)(qt * 64 + wave * 16 + li) * D_HEAD;
        #pragma unroll
        for (int ks = 0; ks < 2; ++ks) {
            const f32x4* s4 = (const f32x4*)(qp + ks * 32 + lg * 8);
            f32x4 a = s4[0], b = s4[1];
            union { unsigned short u[8]; bf16x8 v; } w;
            #pragma unroll
            for (int e = 0; e < 4; ++e) {
                w.u[e]     = f2bf(a[e] * QSCALE);
                w.u[4 + e] = f2bf(b[e] * QSCALE);
            }
            qfrag[ks] = w.v;
        }
    }

    f32x4 acc[4];
    #pragma unroll
    for (int dc = 0; dc < 4; ++dc) { f32x4 z = {0.f,0.f,0.f,0.f}; acc[dc] = z; }
    float mrun = -1e30f, lrun = 0.f;

    const int kr = tid >> 2, kq = tid & 3;
    const int vp = tid >> 3, vc = tid & 7;

    f32x4 kreg[4], vreg[4];

#define ISSUE_LOADS(kt_) do {                                                          \
        const f32x4* ks4_ = (const f32x4*)(Kb + (size_t)((kt_) * KBLK + kr) * D_HEAD + kq * 16); \
        kreg[0] = ks4_[0]; kreg[1] = ks4_[1]; kreg[2] = ks4_[2]; kreg[3] = ks4_[3];    \
        const float* r0_ = Vb + (size_t)((kt_) * KBLK + 2 * vp) * D_HEAD + vc * 8;     \
        const f32x4* v0_ = (const f32x4*)r0_;                                          \
        const f32x4* v1_ = (const f32x4*)(r0_ + D_HEAD);                               \
        vreg[0] = v0_[0]; vreg[1] = v0_[1]; vreg[2] = v1_[0]; vreg[3] = v1_[1];        \
    } while (0)

#define WRITE_LDS(bufi_) do {                                                          \
        unsigned short* Klb_ = &KlBuf[bufi_][0];                                       \
        unsigned short* Vtb_ = &VtBuf[bufi_][0];                                       \
        union { unsigned short u[8]; ushort8_t v8; } w0_, w1_;                         \
        _Pragma("unroll")                                                              \
        for (int e = 0; e < 4; ++e) {                                                  \
            w0_.u[e]   = f2bf(kreg[0][e]); w0_.u[4+e] = f2bf(kreg[1][e]);              \
            w1_.u[e]   = f2bf(kreg[2][e]); w1_.u[4+e] = f2bf(kreg[3][e]);              \
        }                                                                              \
        *(ushort8_t*)&Klb_[swz(kr, kq * 32     ) >> 1] = w0_.v8;                       \
        *(ushort8_t*)&Klb_[swz(kr, kq * 32 + 16) >> 1] = w1_.v8;                       \
        _Pragma("unroll")                                                              \
        for (int e = 0; e < 8; ++e) {                                                  \
            float lo_ = (e < 4) ? vreg[0][e] : vreg[1][e - 4];                         \
            float hi_ = (e < 4) ? vreg[2][e] : vreg[3][e - 4];                         \
            unsigned pk_ = (unsigned)f2bf(lo_) | ((unsigned)f2bf(hi_) << 16);          \
            *(unsigned*)&Vtb_[swz(vc * 8 + e, vp * 4) >> 1] = pk_;                     \
        }                                                                              \
    } while (0)

    ISSUE_LOADS(0);
    WRITE_LDS(0);
    ISSUE_LOADS(1);
    asm volatile("s_waitcnt lgkmcnt(0)\n\ts_barrier" ::: "memory");

    for (int kt = 0; kt < NKT; ++kt) {
        const unsigned short* Klb = &KlBuf[kt & 1][0];
        const unsigned short* Vtb = &VtBuf[kt & 1][0];

        f32x4 s[4];
        #pragma unroll
        for (int nc = 0; nc < 4; ++nc) { f32x4 z = {0.f,0.f,0.f,0.f}; s[nc] = z; }
        #pragma unroll
        for (int nc = 0; nc < 4; ++nc) {
            #pragma unroll
            for (int ks = 0; ks < 2; ++ks) {
                bf16x8 kf = *(const bf16x8*)&Klb[swz(nc * 16 + li, ks * 64 + lg * 16) >> 1];
                s[nc] = __builtin_amdgcn_mfma_f32_16x16x32_bf16(kf, qfrag[ks], s[nc], 0, 0, 0);
            }
        }

        float t = s[0][0];
        #pragma unroll
        for (int nc = 0; nc < 4; ++nc)
            #pragma unroll
            for (int rr = 0; rr < 4; ++rr)
                t = fmaxf(t, s[nc][rr]);
        t = fmaxf(t, __shfl_xor(t, 16));
        t = fmaxf(t, __shfl_xor(t, 32));

        if (__any(t > mrun + 8.0f)) {
            const float mn  = fmaxf(mrun, t);
            const float fac = __builtin_amdgcn_exp2f(mrun - mn);
            mrun = mn;
            lrun *= fac;
            #pragma unroll
            for (int dc = 0; dc < 4; ++dc)
                #pragma unroll
                for (int rr = 0; rr < 4; ++rr)
                    acc[dc][rr] *= fac;
        }

        float p[4][4];
        float rs = 0.f;
        #pragma unroll
        for (int nc = 0; nc < 4; ++nc)
            #pragma unroll
            for (int rr = 0; rr < 4; ++rr) {
                p[nc][rr] = __builtin_amdgcn_exp2f(s[nc][rr] - mrun);
                rs += p[nc][rr];
            }
        rs += __shfl_xor(rs, 16);
        rs += __shfl_xor(rs, 32);
        lrun += rs;

        #pragma unroll
        for (int nc = 0; nc < 4; ++nc) {
            union { unsigned short u[4]; unsigned long long ll; } w;
            #pragma unroll
            for (int rr = 0; rr < 4; ++rr) w.u[rr] = f2bf(p[nc][rr]);
            *(unsigned long long*)&Pl[wave][swz(li, nc * 32 + lg * 8) >> 1] = w.ll;
        }

        #pragma unroll
        for (int ks = 0; ks < 2; ++ks) {
            bf16x8 pa = *(const bf16x8*)&Pl[wave][swz(li, ks * 64 + lg * 16) >> 1];
            #pragma unroll
            for (int dc = 0; dc < 4; ++dc) {
                bf16x8 vf = *(const bf16x8*)&Vtb[swz(dc * 16 + li, ks * 64 + lg * 16) >> 1];
                acc[dc] = __builtin_amdgcn_mfma_f32_16x16x32_bf16(vf, pa, acc[dc], 0, 0, 0);
            }
        }

        if (kt < NKT - 1) {
            WRITE_LDS((kt + 1) & 1);
            if (kt + 2 < NKT) ISSUE_LOADS(kt + 2);
            asm volatile("s_waitcnt lgkmcnt(0)\n\ts_barrier" ::: "memory");
        }
    }

    const float inv = 1.0f / lrun;
    const int orow = qt * 64 + wave * 16 + li;
    #pragma unroll
    for (int dc = 0; dc < 4; ++dc) {
        f32x4 o;
        #pragma unroll
        for (int rr = 0; rr < 4; ++rr) o[rr] = acc[dc][rr] * inv;
        *(f32x4*)&Ob[(size_t)orow * D_HEAD + dc * 16 + lg * 4] = o;
    }
#undef ISSUE_LOADS
#undef WRITE_LDS
}

extern "C" void kernel_launch(void* const* d_in, const int* in_sizes, int n_in,
                              void* d_out, int out_size, void* d_ws, size_t ws_size,
                              hipStream_t stream) {
    const float* Q = (const float*)d_in[0];
    const float* K = (const float*)d_in[1];
    const float* V = (const float*)d_in[2];
    float* O = (float*)d_out;

    const size_t img_elems = (size_t)NHEADS * NKT * TILE_ELEMS;
    const size_t need = img_elems * 2 * 2;   // bf16, K+V = 25.2 MB

    if (ws_size >= need) {
        unsigned short* Kimg = (unsigned short*)d_ws;
        unsigned short* Vimg = Kimg + img_elems;
        prep_kv6<<<dim3(NHEADS * NKT), dim3(256), 0, stream>>>(K, V, Kimg, Vimg);
        attn_fwd15<<<dim3(NHEADS * 8), dim3(256), 0, stream>>>(Q, Kimg, Vimg, O);
    } else {
        attn_fwd4<<<dim3(NHEADS * 16), dim3(256), 0, stream>>>(Q, K, V, O);
    }
}